// Round 5
// baseline (3776.485 us; speedup 1.0000x reference)
//
#include <hip/hip_runtime.h>
#include <stdint.h>

// LSTMModel: 4-layer LSTM (B=256,T=512,H=256,Din=28) + sigmoid proj (21)
// R5: dataflow via epoch-tagged h granules (tag bit in LSB of first bf16 of
// each u64 granule) -> no flags, no drains on the critical path. Phase-split
// K (W_ih part / W_hh part) with prefetched A-panel and rec loads hidden
// under phase-A MFMAs. Ring depth 8, coarse back-pressure every 2 steps.

#define B 256
#define T 512
#define H 256
#define DIN 28
#define NWG 256
#define OUTD 21

typedef __attribute__((ext_vector_type(8))) __bf16 bf16x8;
typedef __attribute__((ext_vector_type(4))) float f32x4;
typedef __attribute__((ext_vector_type(4))) unsigned short u16x4;
typedef unsigned long long u64;

// ---- workspace layout (bytes) ----
#define WS_PROG  0ull                                   // 32 grp * 16 u32 = 2 KB
#define WS_HBUF  2048ull                                // [l][slot8][b][j] bf16: 4 MB
#define WS_XBF   (WS_HBUF + 4ull*8*B*H*2)               // x bf16 [b][t][32]: 8 MB
#define WS_WIH0  (WS_XBF + (u64)B*T*32*2)
#define WS_WIHR  (WS_WIH0 + 1024ull*32*2)
#define WS_WHHR  (WS_WIHR + 3ull*1024*256*2)
#define WS_BIAS  (WS_WHHR + 4ull*1024*256*2)
#define WS_ZERO  WS_HBUF                                // memset: prog only

__device__ __forceinline__ unsigned short f2bf(float f) {
  unsigned u = __builtin_bit_cast(unsigned, f);
  u += 0x7fffu + ((u >> 16) & 1u);
  return (unsigned short)(u >> 16);
}
__device__ __forceinline__ float bf2f(unsigned short v) {
  return __builtin_bit_cast(float, (unsigned)v << 16);
}
__device__ __forceinline__ float sigf(float x) { return 1.f / (1.f + __expf(-x)); }
__device__ __forceinline__ float tanhfast(float x) {
  float e = __expf(2.f * x);
  return 1.f - 2.f / (e + 1.f);
}

__device__ __forceinline__ void stg_coh8(void* p, u64 v) {
  __hip_atomic_store((u64*)p, v, __ATOMIC_RELAXED, __HIP_MEMORY_SCOPE_AGENT);
}
__device__ __forceinline__ u64 ldq(const u64* p) {
  return __hip_atomic_load(p, __ATOMIC_RELAXED, __HIP_MEMORY_SCOPE_AGENT);
}

// ---------------- prep kernels ----------------
__global__ void prep_x(const float* __restrict__ x, unsigned short* __restrict__ xbf) {
  int tot = B * T * 32;
  for (int idx = blockIdx.x * blockDim.x + threadIdx.x; idx < tot;
       idx += gridDim.x * blockDim.x) {
    int kk = idx & 31;
    int bt = idx >> 5;
    float v = (kk < DIN) ? x[(size_t)bt * DIN + kk] : 0.f;
    xbf[idx] = f2bf(v);
  }
}

// fill hbuf with 0x0001 pattern: tag bit 1 (=epoch(-1)) + value ~0
__global__ void prep_fill(u64* __restrict__ hb) {
  const size_t n = 4ull * 8 * B * H / 4;   // u64 granules
  for (size_t i = blockIdx.x * blockDim.x + threadIdx.x; i < n;
       i += (size_t)gridDim.x * blockDim.x)
    hb[i] = 0x0001000100010001ull;
}

__global__ void prep_w(const float* __restrict__ wih0, const float* __restrict__ wihrest,
                       const float* __restrict__ whh, const float* __restrict__ bih,
                       const float* __restrict__ bhh,
                       unsigned short* __restrict__ wih0r, unsigned short* __restrict__ wihr,
                       unsigned short* __restrict__ whhr, float* __restrict__ biasr) {
  const int R0 = 1024 * 32, R1 = 3 * 1024 * 256, R2 = 4 * 1024 * 256, R3 = 4 * 1024;
  int tot = R0 + R1 + R2 + R3;
  for (int idx = blockIdx.x * blockDim.x + threadIdx.x; idx < tot;
       idx += gridDim.x * blockDim.x) {
    if (idx < R0) {
      int k = idx & 31, np = idx >> 5, g = np & 3, j = np >> 2;
      wih0r[idx] = f2bf(k < DIN ? wih0[(size_t)(g * 256 + j) * DIN + k] : 0.f);
    } else if (idx < R0 + R1) {
      int i = idx - R0;
      int k = i & 255, r = i >> 8, np = r & 1023, l = r >> 10, g = np & 3, j = np >> 2;
      wihr[i] = f2bf(wihrest[((size_t)l * 1024 + g * 256 + j) * 256 + k]);
    } else if (idx < R0 + R1 + R2) {
      int i = idx - R0 - R1;
      int k = i & 255, r = i >> 8, np = r & 1023, l = r >> 10, g = np & 3, j = np >> 2;
      whhr[i] = f2bf(whh[((size_t)l * 1024 + g * 256 + j) * 256 + k]);
    } else {
      int i = idx - R0 - R1 - R2;
      int np = i & 1023, l = i >> 10, g = np & 3, j = np >> 2;
      biasr[i] = bih[l * 1024 + g * 256 + j] + bhh[l * 1024 + g * 256 + j];
    }
  }
}

// ---------------- main persistent kernel ----------------
__device__ __forceinline__ bf16x8 lds_frag(const unsigned char* base, int row, int kb) {
  return *(const bf16x8*)(base + row * 1024 + (kb ^ ((row & 15) << 4)));
}

__device__ __forceinline__ void mstep(const unsigned char* Ast, const unsigned char* Ws,
                                      int kb, int ar0, int ar1, int br0, int br1,
                                      f32x4& a00, f32x4& a01, f32x4& a10, f32x4& a11) {
  bf16x8 a0 = lds_frag(Ast, ar0, kb);
  bf16x8 a1 = lds_frag(Ast, ar1, kb);
  bf16x8 b0 = lds_frag(Ws, br0, kb);
  bf16x8 b1 = lds_frag(Ws, br1, kb);
  a00 = __builtin_amdgcn_mfma_f32_16x16x32_bf16(a0, b0, a00, 0, 0, 0);
  a01 = __builtin_amdgcn_mfma_f32_16x16x32_bf16(a0, b1, a01, 0, 0, 0);
  a10 = __builtin_amdgcn_mfma_f32_16x16x32_bf16(a1, b0, a10, 0, 0, 0);
  a11 = __builtin_amdgcn_mfma_f32_16x16x32_bf16(a1, b1, a11, 0, 0, 0);
}

__launch_bounds__(256, 1)
__global__ void lstm_main(const unsigned short* __restrict__ xbf,
                          const unsigned short* __restrict__ wih0r,
                          const unsigned short* __restrict__ wihr,
                          const unsigned short* __restrict__ whhr,
                          const float* __restrict__ biasr,
                          const float* __restrict__ Wout, const float* __restrict__ bout,
                          unsigned short* __restrict__ hbuf, unsigned* __restrict__ prog,
                          float* __restrict__ out) {
  __shared__ unsigned char Ws[64 * 1024];
  __shared__ unsigned char Ap[64 * 1024];
  __shared__ float gates[64 * 68];

  const int tid = threadIdx.x;
  const int lane = tid & 63;
  const int w = tid >> 6;
  const int wb = w >> 1, wn = w & 1;
  const int bid = blockIdx.x;
  const int layer = (bid & 7) >> 1;
  const int wgl = ((bid >> 3) << 1) | (bid & 1);
  const int b0g = wgl >> 4;
  const int b0 = b0g * 64;
  const int ntile = wgl & 15;
  const int n0 = ntile * 64;
  const int j0 = ntile * 16;
  const int mygrp = layer * 4 + b0g;

  // ---- resident weight slice -> LDS ----
  const int ngr = (layer == 0) ? 36 : 64;
  for (int i = tid; i < 64 * ngr; i += 256) {
    int row = i / ngr, blk = i % ngr;
    uint4 v;
    if (layer == 0) {
      if (blk < 4) v = *(const uint4*)(wih0r + (size_t)(n0 + row) * 32 + blk * 8);
      else v = *(const uint4*)(whhr + (size_t)(n0 + row) * 256 + (blk - 4) * 8);
    } else {
      if (blk < 32)
        v = *(const uint4*)(wihr + ((size_t)(layer - 1) * 1024 + n0 + row) * 256 + blk * 8);
      else
        v = *(const uint4*)(whhr + ((size_t)layer * 1024 + n0 + row) * 256 + (blk - 32) * 8);
    }
    *(uint4*)(Ws + row * 1024 + ((blk * 16) ^ ((row & 15) << 4))) = v;
  }
  const float bv0 = biasr[layer * 1024 + n0 + wn * 32 + (lane & 15)];
  const float bv1 = biasr[layer * 1024 + n0 + wn * 32 + 16 + (lane & 15)];
  __syncthreads();

  const int arow0 = wb * 32 + (lane & 15);
  const int arow1 = arow0 + 16;
  const int akoff2 = (lane >> 4) * 16;
  const int brow0 = wn * 32 + (lane & 15);
  const int brow1 = brow0 + 16;

  const int scol = tid & 31;   // 16B column within half-panel
  const int srow = tid >> 5;   // base row (stride 8)
  const int xcol = tid & 3;    // layer-0 x staging
  const int xrow = tid >> 2;

  const int recbase = (layer == 0) ? 64 : 512;   // byte offset of rec K in panel rows

  f32x4 creg = {0.f, 0.f, 0.f, 0.f};
  u64 pA[16], rr[16], pr[8];

  // ---- prologue: issue A-panel loads for t=0 ----
  if (layer == 0) {
    const u64* s = (const u64*)(xbf + ((size_t)(b0 + xrow) * T + 0) * 32 + xcol * 8);
    pA[0] = s[0];
    pA[1] = s[1];
  } else {
    const unsigned short* hbP = hbuf + ((size_t)(layer - 1) * 8 + 0) * 65536;
#pragma unroll
    for (int i = 0; i < 8; ++i) {
      const u64* s = (const u64*)(hbP + (size_t)(b0 + srow + 8 * i) * 256 + scol * 8);
      pA[2 * i] = ldq(s);
      pA[2 * i + 1] = ldq(s + 1);
    }
  }

  for (int t = 0; t < T; ++t) {
    const unsigned e_t = ((unsigned)t >> 3) & 1u;                 // epoch(t)
    const unsigned e_rec = ((((unsigned)t + 7) >> 3) & 1u) ^ 1u;  // epoch(t-1)
    const bool bp = (layer < 3) && (t >= 8) && ((t & 1) == 0);    // back-pressure check step

    // ---- phase A: validate prefetched panel, write to LDS ----
    if (layer == 0) {
      uint4 v;
      ((u64*)&v)[0] = pA[0];
      ((u64*)&v)[1] = pA[1];
      *(uint4*)(Ap + xrow * 1024 + ((xcol * 16) ^ ((xrow & 15) << 4))) = v;
    } else {
      const unsigned short* hbP = hbuf + ((size_t)(layer - 1) * 8 + (t & 7)) * 65536;
      for (;;) {
        u64 bad = 0;
#pragma unroll
        for (int i = 0; i < 16; ++i) bad |= (pA[i] ^ (u64)e_t) & 1ull;
        if (!bad) break;
        __builtin_amdgcn_s_sleep(1);
#pragma unroll
        for (int i = 0; i < 8; ++i) {
          const u64* s = (const u64*)(hbP + (size_t)(b0 + srow + 8 * i) * 256 + scol * 8);
          pA[2 * i] = ldq(s);
          pA[2 * i + 1] = ldq(s + 1);
        }
      }
#pragma unroll
      for (int i = 0; i < 8; ++i) {
        int row = srow + 8 * i;
        uint4 v;
        ((u64*)&v)[0] = pA[2 * i];
        ((u64*)&v)[1] = pA[2 * i + 1];
        *(uint4*)(Ap + row * 1024 + ((scol * 16) ^ ((row & 15) << 4))) = v;
      }
    }

    // ---- issue rec-panel loads (validated after phase-A compute) ----
    const unsigned short* hbR = hbuf + ((size_t)layer * 8 + ((t - 1) & 7)) * 65536;
#pragma unroll
    for (int i = 0; i < 8; ++i) {
      const u64* s = (const u64*)(hbR + (size_t)(b0 + srow + 8 * i) * 256 + scol * 8);
      rr[2 * i] = ldq(s);
      rr[2 * i + 1] = ldq(s + 1);
    }
    __builtin_amdgcn_sched_barrier(0);
    __syncthreads();   // A panel visible

    // ---- phase-A MFMAs (covers rec load latency) ----
    f32x4 a00 = {bv0, bv0, bv0, bv0};
    f32x4 a01 = {bv1, bv1, bv1, bv1};
    f32x4 a10 = a00, a11 = a01;
    if (layer == 0) {
      mstep(Ap, Ws, akoff2, arow0, arow1, brow0, brow1, a00, a01, a10, a11);
    } else {
#pragma unroll
      for (int ki = 0; ki < 8; ++ki)
        mstep(Ap, Ws, ki * 64 + akoff2, arow0, arow1, brow0, brow1, a00, a01, a10, a11);
    }

    // ---- validate rec granules, write to LDS ----
    for (;;) {
      u64 bad = 0;
#pragma unroll
      for (int i = 0; i < 16; ++i) bad |= (rr[i] ^ (u64)e_rec) & 1ull;
      if (!bad) break;
      __builtin_amdgcn_s_sleep(1);
#pragma unroll
      for (int i = 0; i < 8; ++i) {
        const u64* s = (const u64*)(hbR + (size_t)(b0 + srow + 8 * i) * 256 + scol * 8);
        rr[2 * i] = ldq(s);
        rr[2 * i + 1] = ldq(s + 1);
      }
    }
#pragma unroll
    for (int i = 0; i < 8; ++i) {
      int row = srow + 8 * i;
      uint4 v;
      ((u64*)&v)[0] = rr[2 * i];
      ((u64*)&v)[1] = rr[2 * i + 1];
      *(uint4*)(Ap + row * 1024 + ((recbase + scol * 16) ^ ((row & 15) << 4))) = v;
    }

    // ---- issue back-pressure prog loads + A-panel prefetch for t+1 ----
    if (bp) {
      const u64* dp = (const u64*)(prog + (size_t)(mygrp + 4) * 16);
#pragma unroll
      for (int i = 0; i < 8; ++i) pr[i] = ldq(dp + i);
    }
    if (t + 1 < T) {
      if (layer == 0) {
        const u64* s = (const u64*)(xbf + ((size_t)(b0 + xrow) * T + (t + 1)) * 32 + xcol * 8);
        pA[0] = s[0];
        pA[1] = s[1];
      } else {
        const unsigned short* hbP2 = hbuf + ((size_t)(layer - 1) * 8 + ((t + 1) & 7)) * 65536;
#pragma unroll
        for (int i = 0; i < 8; ++i) {
          const u64* s = (const u64*)(hbP2 + (size_t)(b0 + srow + 8 * i) * 256 + scol * 8);
          pA[2 * i] = ldq(s);
          pA[2 * i + 1] = ldq(s + 1);
        }
      }
    }
    __builtin_amdgcn_sched_barrier(0);
    __syncthreads();   // rec panel visible

    // ---- phase-R MFMAs ----
    if (layer == 0) {
#pragma unroll
      for (int ki = 1; ki < 9; ++ki)
        mstep(Ap, Ws, ki * 64 + akoff2, arow0, arow1, brow0, brow1, a00, a01, a10, a11);
    } else {
#pragma unroll
      for (int ki = 8; ki < 16; ++ki)
        mstep(Ap, Ws, ki * 64 + akoff2, arow0, arow1, brow0, brow1, a00, a01, a10, a11);
    }

    // ---- scatter acc frags to gates[n'rel][brel] ----
    {
      int c = lane & 15, Rg = lane >> 4;
      *(f32x4*)&gates[(wn * 32 + c) * 68 + wb * 32 + Rg * 4] = a00;
      *(f32x4*)&gates[(wn * 32 + 16 + c) * 68 + wb * 32 + Rg * 4] = a01;
      *(f32x4*)&gates[(wn * 32 + c) * 68 + wb * 32 + 16 + Rg * 4] = a10;
      *(f32x4*)&gates[(wn * 32 + 16 + c) * 68 + wb * 32 + 16 + Rg * 4] = a11;
    }
    __syncthreads();

    // ---- activations + cell update + tagged h store ----
    {
      int brel = tid & 63, jq = tid >> 6;
      int b = b0 + brel;
      int jb = j0 + jq * 4;
      f32x4 cnew;
      float hv[4];
#pragma unroll
      for (int i2 = 0; i2 < 4; ++i2) {
        int jr = jq * 4 + i2;
        float ip = gates[(4 * jr + 0) * 68 + brel];
        float fp = gates[(4 * jr + 1) * 68 + brel];
        float gp = gates[(4 * jr + 2) * 68 + brel];
        float op = gates[(4 * jr + 3) * 68 + brel];
        float ii = sigf(ip), ff = sigf(fp), gg = tanhfast(gp), oo = sigf(op);
        float cc = ff * creg[i2] + ii * gg;
        cnew[i2] = cc;
        hv[i2] = oo * tanhfast(cc);
      }
      creg = cnew;

      // back-pressure gate before overwriting ring slot t (destroys t-8, t-7)
      if (bp) {
        const u64* dp = (const u64*)(prog + (size_t)(mygrp + 4) * 16);
        const unsigned need = (unsigned)(t - 6);
        for (;;) {
          unsigned mn = 0xFFFFFFFFu;
#pragma unroll
          for (int i = 0; i < 8; ++i) {
            unsigned lo = (unsigned)pr[i], hi = (unsigned)(pr[i] >> 32);
            mn = mn < lo ? mn : lo;
            mn = mn < hi ? mn : hi;
          }
          if (mn >= need) break;
          __builtin_amdgcn_s_sleep(1);
#pragma unroll
          for (int i = 0; i < 8; ++i) pr[i] = ldq(dp + i);
        }
      }

      u16x4 h4 = {(unsigned short)((f2bf(hv[0]) & 0xFFFEu) | e_t), f2bf(hv[1]),
                  f2bf(hv[2]), f2bf(hv[3])};
      stg_coh8(hbuf + ((size_t)layer * 8 + (t & 7)) * 65536 + (size_t)b * H + jb,
               __builtin_bit_cast(u64, h4));
    }
    // publish coarse progress every 2 steps
    if (((t & 1) == 1) && tid == 0)
      __hip_atomic_store(&prog[mygrp * 16 + ntile], (unsigned)(t + 1), __ATOMIC_RELAXED,
                         __HIP_MEMORY_SCOPE_AGENT);
  }

  // ---- final projection by layer-3 WGs: 4 b each, h from tagged hbuf ----
  if (layer == 3) {
    const unsigned short* hp = hbuf + ((size_t)3 * 8 + ((T - 1) & 7)) * 65536;
    const unsigned efin = (((unsigned)(T - 1)) >> 3) & 1u;
    int bi = tid >> 6, gcol = tid & 63;
    int brow = b0 + ntile * 4 + bi;
    const u64* s = (const u64*)(hp + (size_t)brow * 256 + gcol * 4);
    u64 v;
    for (;;) {
      v = ldq(s);
      if (((unsigned)v & 1u) == efin) break;
      __builtin_amdgcn_s_sleep(1);
    }
    gates[bi * 260 + gcol * 4 + 0] = bf2f((unsigned short)v);
    gates[bi * 260 + gcol * 4 + 1] = bf2f((unsigned short)(v >> 16));
    gates[bi * 260 + gcol * 4 + 2] = bf2f((unsigned short)(v >> 32));
    gates[bi * 260 + gcol * 4 + 3] = bf2f((unsigned short)(v >> 48));
    __syncthreads();
    if (tid < 4 * OUTD) {
      int o = tid % OUTD, bj = tid / OUTD;
      int b = b0 + ntile * 4 + bj;
      const float* wr = Wout + (size_t)o * H;
      const float* hr = &gates[bj * 260];
      float sum = bout[o];
#pragma unroll 8
      for (int j = 0; j < H; ++j) sum = fmaf(hr[j], wr[j], sum);
      out[b * OUTD + o] = sigf(sum);
    }
  }
}

extern "C" void kernel_launch(void* const* d_in, const int* in_sizes, int n_in,
                              void* d_out, int out_size, void* d_ws, size_t ws_size,
                              hipStream_t stream) {
  const float* x = (const float*)d_in[0];
  const float* Wih0 = (const float*)d_in[1];
  const float* WihRest = (const float*)d_in[2];
  const float* Whh = (const float*)d_in[3];
  const float* bih = (const float*)d_in[4];
  const float* bhh = (const float*)d_in[5];
  const float* Wout = (const float*)d_in[6];
  const float* bout = (const float*)d_in[7];
  float* out = (float*)d_out;
  char* ws = (char*)d_ws;

  unsigned* prog = (unsigned*)(ws + WS_PROG);
  unsigned short* hbuf = (unsigned short*)(ws + WS_HBUF);
  unsigned short* xbf = (unsigned short*)(ws + WS_XBF);
  unsigned short* wih0r = (unsigned short*)(ws + WS_WIH0);
  unsigned short* wihr = (unsigned short*)(ws + WS_WIHR);
  unsigned short* whhr = (unsigned short*)(ws + WS_WHHR);
  float* biasr = (float*)(ws + WS_BIAS);

  hipMemsetAsync(ws, 0, (size_t)WS_ZERO, stream);
  prep_fill<<<1024, 256, 0, stream>>>((u64*)hbuf);
  prep_x<<<2048, 256, 0, stream>>>(x, xbf);
  prep_w<<<2048, 256, 0, stream>>>(Wih0, WihRest, Whh, bih, bhh, wih0r, wihr, whhr, biasr);
  lstm_main<<<NWG, 256, 0, stream>>>(xbf, wih0r, wihr, whhr, biasr, Wout, bout, hbuf,
                                     prog, out);
}